// Round 1
// baseline (2655.395 us; speedup 1.0000x reference)
//
#include <hip/hip_runtime.h>
#include <math.h>

#define T_SAMPLES 96000
#define NFRAMES 801
#define NBINS 513
#define EPS32 1.1920928955078125e-07f

// ---------------------------------------------------------------- STFT ----
// One block per (frame, batch). 512 threads, 1024-pt Stockham radix-2 FFT
// in LDS (ping-pong), real input (windowed), imag=0. Natural-order output.
__global__ __launch_bounds__(512) void stft_kernel(const float* __restrict__ y,
                                                   float* __restrict__ mag)
{
    int t = blockIdx.x;   // frame 0..800
    int b = blockIdx.y;   // batch 0..3
    int tid = threadIdx.x;

    __shared__ float2 buf[2][1024];

    const float* yb = y + (size_t)b * T_SAMPLES;
    for (int n = tid; n < 1024; n += 512) {
        int j = t * 120 + n - 512;          // reflect pad 512 both sides
        if (j < 0) j = -j;
        if (j >= T_SAMPLES) j = 2 * T_SAMPLES - 2 - j;
        float v = yb[j];
        int np_ = n - 212;                  // window placed at lp=212, len 600
        float w = 0.0f;
        if (np_ >= 0 && np_ < 600)
            w = 0.5f * (1.0f - cospif((float)np_ * (1.0f / 300.0f)));
        buf[0][n] = make_float2(v * w, 0.0f);
    }
    __syncthreads();

    int srcb = 0;
    #pragma unroll
    for (int stage = 0; stage < 10; ++stage) {
        int m  = 1 << stage;
        int jm = (tid >> stage) << stage;   // j*m
        float jf = (float)jm * (1.0f / 512.0f);
        float wr = cospif(jf);
        float wi = -sinpif(jf);             // e^{-i pi j/l}
        float2 a  = buf[srcb][tid];
        float2 bb = buf[srcb][tid + 512];
        float2 s  = make_float2(a.x + bb.x, a.y + bb.y);
        float2 d  = make_float2(a.x - bb.x, a.y - bb.y);
        float2 dw = make_float2(d.x * wr - d.y * wi, d.x * wi + d.y * wr);
        buf[srcb ^ 1][tid + jm]     = s;
        buf[srcb ^ 1][tid + jm + m] = dw;
        __syncthreads();
        srcb ^= 1;
    }

    float2 v = buf[srcb][tid];
    float msq = v.x * v.x + v.y * v.y;
    mag[((size_t)b * NBINS + tid) * NFRAMES + t] = sqrtf(fmaxf(msq, EPS32));
    if (tid == 0) {
        float2 v5 = buf[srcb][512];
        float m5 = v5.x * v5.x + v5.y * v5.y;
        mag[((size_t)b * NBINS + 512) * NFRAMES + t] = sqrtf(fmaxf(m5, EPS32));
    }
}

// ---------------------------------------------------------- weight norm ----
// One block per output channel: wn = g[o] * v / ||v[o]||_2
__global__ __launch_bounds__(256) void wnorm_kernel(const float* __restrict__ v,
                                                    const float* __restrict__ g,
                                                    float* __restrict__ out, int per_o)
{
    int o = blockIdx.x;
    int tid = threadIdx.x;
    __shared__ float red[256];
    const float* vo = v + (size_t)o * per_o;
    float s = 0.f;
    for (int i = tid; i < per_o; i += 256) { float x = vo[i]; s = fmaf(x, x, s); }
    red[tid] = s;
    __syncthreads();
    for (int k = 128; k > 0; k >>= 1) {
        if (tid < k) red[tid] += red[tid + k];
        __syncthreads();
    }
    float scale = g[o] / sqrtf(red[0]);
    for (int i = tid; i < per_o; i += 256) out[(size_t)o * per_o + i] = vo[i] * scale;
}

// -------------------------------------------------------- harmonic conv ----
// lowered channels 0..3 are identically zero (shift >= F). Channels 4,5,6:
// frac blends of rows f-336/f-337, f-154/f-155, and f. 1x7 conv, pad (0,3).
__global__ __launch_bounds__(256) void harmonic_kernel(const float* __restrict__ mag,
                                                       const float* __restrict__ wn,
                                                       const float* __restrict__ bias,
                                                       float* __restrict__ out,
                                                       float fr4, float fr5)
{
    int t = blockIdx.x * 256 + threadIdx.x;
    int f = blockIdx.y;
    int b = blockIdx.z;
    if (t >= NFRAMES) return;

    const float* mb = mag + (size_t)b * NBINS * NFRAMES;
    float xv[3][7];
    #pragma unroll
    for (int kw = 0; kw < 7; ++kw) {
        int tt = t + kw - 3;
        bool ok = (tt >= 0) && (tt < NFRAMES);
        float m336 = (ok && f >= 336) ? mb[(size_t)(f - 336) * NFRAMES + tt] : 0.f;
        float m337 = (ok && f >= 337) ? mb[(size_t)(f - 337) * NFRAMES + tt] : 0.f;
        xv[0][kw] = (1.f - fr4) * m336 + fr4 * m337;
        float m154 = (ok && f >= 154) ? mb[(size_t)(f - 154) * NFRAMES + tt] : 0.f;
        float m155 = (ok && f >= 155) ? mb[(size_t)(f - 155) * NFRAMES + tt] : 0.f;
        xv[1][kw] = (1.f - fr5) * m154 + fr5 * m155;
        xv[2][kw] = ok ? mb[(size_t)f * NFRAMES + tt] : 0.f;
    }

    for (int o = 0; o < 32; ++o) {
        float a = bias[o];
        #pragma unroll
        for (int ci = 0; ci < 3; ++ci) {
            int c = 4 + ci;
            #pragma unroll
            for (int kw = 0; kw < 7; ++kw)
                a = fmaf(xv[ci][kw], wn[(o * 7 + c) * 7 + kw], a);
        }
        a = (a > 0.f) ? a : 0.1f * a;
        out[(((size_t)b * 32 + o) * NBINS + f) * NFRAMES + t] = a;
    }
}

// ------------------------------------------------------------ conv stack ----
// C=32 -> O=32, kernel 3 x KW, freq pad 1, time pad PW, time stride STRIDE.
// Block: 64 t-positions x 4 wave-aligned o-groups (8 o each). Input row
// staged in LDS; weights via wave-uniform scalar loads.
template<int KW, int STRIDE, int PW, bool DO_LRELU>
__global__ __launch_bounds__(256) void conv2d_kernel(const float* __restrict__ in,
                                                     const float* __restrict__ wn,
                                                     const float* __restrict__ bias,
                                                     float* __restrict__ out,
                                                     int Tin, int Tout)
{
    constexpr int XW  = 63 * STRIDE + KW;   // staged row width
    constexpr int WPO = 32 * 3 * KW;        // weights per output channel
    __shared__ float xs[3][XW];

    int t0  = blockIdx.x * 64;
    int f   = blockIdx.y;
    int b   = blockIdx.z;
    int tid = threadIdx.x;
    int tt  = tid & 63;
    int og  = tid >> 6;
    int obase = __builtin_amdgcn_readfirstlane(og << 3);

    float acc[8];
    #pragma unroll
    for (int i = 0; i < 8; ++i) acc[i] = 0.f;

    int tbase = t0 * STRIDE - PW;
    const float* inb = in + (size_t)b * 32 * NBINS * Tin;

    for (int c = 0; c < 32; ++c) {
        __syncthreads();
        for (int i = tid; i < 3 * XW; i += 256) {
            int df = i / XW, x = i - df * XW;
            int fi = f + df - 1;
            int ti = tbase + x;
            float v = 0.f;
            if (fi >= 0 && fi < NBINS && ti >= 0 && ti < Tin)
                v = inb[((size_t)c * NBINS + fi) * Tin + ti];
            xs[df][x] = v;
        }
        __syncthreads();

        const float* wrow = wn + (size_t)obase * WPO + c * 3 * KW;
        #pragma unroll
        for (int df = 0; df < 3; ++df) {
            float xv[KW];
            #pragma unroll
            for (int kw = 0; kw < KW; ++kw) xv[kw] = xs[df][tt * STRIDE + kw];
            #pragma unroll
            for (int oi = 0; oi < 8; ++oi) {
                float a = acc[oi];
                #pragma unroll
                for (int kw = 0; kw < KW; ++kw)
                    a = fmaf(xv[kw], wrow[oi * WPO + df * KW + kw], a);
                acc[oi] = a;
            }
        }
    }

    int t = t0 + tt;
    if (t < Tout) {
        #pragma unroll
        for (int oi = 0; oi < 8; ++oi) {
            int o = obase + oi;
            float r = acc[oi] + bias[o];
            if (DO_LRELU) r = (r > 0.f) ? r : 0.1f * r;
            out[(((size_t)b * 32 + o) * NBINS + f) * Tout + t] = r;
        }
    }
}

// ------------------------------------------------------------ final conv ----
// 32 -> 1 channel, 3x3, pad 1, no lrelu. Writes fmap5 AND flat (identical).
__global__ __launch_bounds__(256) void convo_kernel(const float* __restrict__ in,
                                                    const float* __restrict__ wn,
                                                    const float* __restrict__ bias,
                                                    float* __restrict__ f5,
                                                    float* __restrict__ flat)
{
    int idx = blockIdx.x * 256 + threadIdx.x;
    if (idx >= 4 * NBINS * 101) return;
    int t = idx % 101;
    int rem = idx / 101;
    int f = rem % NBINS;
    int b = rem / NBINS;

    float a = bias[0];
    const float* inb = in + (size_t)b * 32 * NBINS * 101;
    for (int c = 0; c < 32; ++c) {
        #pragma unroll
        for (int df = 0; df < 3; ++df) {
            int fi = f + df - 1;
            if (fi < 0 || fi >= NBINS) continue;
            #pragma unroll
            for (int kw = 0; kw < 3; ++kw) {
                int ti = t + kw - 1;
                if (ti < 0 || ti >= 101) continue;
                a = fmaf(inb[((size_t)c * NBINS + fi) * 101 + ti], wn[(c * 3 + df) * 3 + kw], a);
            }
        }
    }
    f5[idx] = a;
    flat[idx] = a;
}

// ------------------------------------------------------------------ launch --
extern "C" void kernel_launch(void* const* d_in, const int* in_sizes, int n_in,
                              void* d_out, int out_size, void* d_ws, size_t ws_size,
                              hipStream_t stream)
{
    const float* y  = (const float*)d_in[0];
    const float* v0 = (const float*)d_in[1];
    const float* g0 = (const float*)d_in[2];
    const float* b0 = (const float*)d_in[3];
    const float* v1 = (const float*)d_in[4];
    const float* g1 = (const float*)d_in[5];
    const float* b1 = (const float*)d_in[6];
    const float* v2 = (const float*)d_in[7];
    const float* g2 = (const float*)d_in[8];
    const float* b2 = (const float*)d_in[9];
    const float* v3 = (const float*)d_in[10];
    const float* g3 = (const float*)d_in[11];
    const float* b3 = (const float*)d_in[12];
    const float* v4 = (const float*)d_in[13];
    const float* g4 = (const float*)d_in[14];
    const float* b4 = (const float*)d_in[15];
    const float* vo = (const float*)d_in[16];
    const float* go = (const float*)d_in[17];
    const float* bo = (const float*)d_in[18];

    float* out = (float*)d_out;
    float* ws  = (float*)d_ws;

    // output regions (concatenated flat in return order)
    const size_t SFLAT = (size_t)4 * NBINS * 101;          //   207,252
    const size_t NF0   = (size_t)4 * 32 * NBINS * 801;     // 52,596,864
    const size_t NF1   = (size_t)4 * 32 * NBINS * 401;     // 26,331,264
    const size_t NF2   = (size_t)4 * 32 * NBINS * 201;     // 13,198,464
    const size_t NF3   = (size_t)4 * 32 * NBINS * 101;     //  6,632,064
    float* oflat = out;
    float* f0 = out + SFLAT;
    float* f1 = f0 + NF0;
    float* f2 = f1 + NF1;
    float* f3 = f2 + NF2;
    float* f4 = f3 + NF3;
    float* f5 = f4 + NF3;

    // mag (4 x 513 x 801) stashed in the (not yet written) fmap1 region;
    // it is consumed by harmonic_kernel before conv1 overwrites f1.
    float* mag = f1;

    // normalized weights in workspace (376 KB)
    size_t off = 0;
    float* w0n = ws + off; off += 1568;
    float* w1n = ws + off; off += 27648;
    float* w2n = ws + off; off += 27648;
    float* w3n = ws + off; off += 27648;
    float* w4n = ws + off; off += 9216;
    float* won = ws + off; off += 288;

    wnorm_kernel<<<32, 256, 0, stream>>>(v0, g0, w0n, 49);
    wnorm_kernel<<<32, 256, 0, stream>>>(v1, g1, w1n, 864);
    wnorm_kernel<<<32, 256, 0, stream>>>(v2, g2, w2n, 864);
    wnorm_kernel<<<32, 256, 0, stream>>>(v3, g3, w3n, 864);
    wnorm_kernel<<<32, 256, 0, stream>>>(v4, g4, w4n, 288);
    wnorm_kernel<<< 1, 256, 0, stream>>>(vo, go, won, 288);

    stft_kernel<<<dim3(NFRAMES, 4), 512, 0, stream>>>(y, mag);

    // fractional shift constants (match numpy float64 SHIFTS computation)
    double sh4 = -(1000.0 * log(0.001 * (5.0 / 7.0)) - 1000.0 * log(0.001)); // 336.472...
    double sh5 = -(1000.0 * log(0.001 * (6.0 / 7.0)) - 1000.0 * log(0.001)); // 154.150...
    float fr4 = (float)(sh4 - floor(sh4));
    float fr5 = (float)(sh5 - floor(sh5));

    harmonic_kernel<<<dim3(4, NBINS, 4), 256, 0, stream>>>(mag, w0n, b0, f0, fr4, fr5);

    conv2d_kernel<9, 2, 4, true><<<dim3(7, NBINS, 4), 256, 0, stream>>>(f0, w1n, b1, f1, 801, 401);
    conv2d_kernel<9, 2, 4, true><<<dim3(4, NBINS, 4), 256, 0, stream>>>(f1, w2n, b2, f2, 401, 201);
    conv2d_kernel<9, 2, 4, true><<<dim3(2, NBINS, 4), 256, 0, stream>>>(f2, w3n, b3, f3, 201, 101);
    conv2d_kernel<3, 1, 1, true><<<dim3(2, NBINS, 4), 256, 0, stream>>>(f3, w4n, b4, f4, 101, 101);

    convo_kernel<<<(int)((4 * NBINS * 101 + 255) / 256), 256, 0, stream>>>(f4, won, bo, f5, oflat);
}

// Round 2
// 829.262 us; speedup vs baseline: 3.2021x; 3.2021x over previous
//
#include <hip/hip_runtime.h>
#include <math.h>

#define T_SAMPLES 96000
#define NFRAMES 801
#define NBINS 513
#define EPS32 1.1920928955078125e-07f

typedef _Float16 f16;
typedef f16 f16x2 __attribute__((ext_vector_type(2)));
typedef f16 f16x8 __attribute__((ext_vector_type(8)));
typedef float f32x4 __attribute__((ext_vector_type(4)));

// ---------------------------------------------------------------- STFT ----
__global__ __launch_bounds__(512) void stft_kernel(const float* __restrict__ y,
                                                   float* __restrict__ mag)
{
    int t = blockIdx.x;   // frame 0..800
    int b = blockIdx.y;   // batch 0..3
    int tid = threadIdx.x;

    __shared__ float2 buf[2][1024];

    const float* yb = y + (size_t)b * T_SAMPLES;
    for (int n = tid; n < 1024; n += 512) {
        int j = t * 120 + n - 512;          // reflect pad 512 both sides
        if (j < 0) j = -j;
        if (j >= T_SAMPLES) j = 2 * T_SAMPLES - 2 - j;
        float v = yb[j];
        int np_ = n - 212;                  // window placed at lp=212, len 600
        float w = 0.0f;
        if (np_ >= 0 && np_ < 600)
            w = 0.5f * (1.0f - cospif((float)np_ * (1.0f / 300.0f)));
        buf[0][n] = make_float2(v * w, 0.0f);
    }
    __syncthreads();

    int srcb = 0;
    #pragma unroll
    for (int stage = 0; stage < 10; ++stage) {
        int m  = 1 << stage;
        int jm = (tid >> stage) << stage;   // j*m
        float jf = (float)jm * (1.0f / 512.0f);
        float wr = cospif(jf);
        float wi = -sinpif(jf);             // e^{-i pi j/l}
        float2 a  = buf[srcb][tid];
        float2 bb = buf[srcb][tid + 512];
        float2 s  = make_float2(a.x + bb.x, a.y + bb.y);
        float2 d  = make_float2(a.x - bb.x, a.y - bb.y);
        float2 dw = make_float2(d.x * wr - d.y * wi, d.x * wi + d.y * wr);
        buf[srcb ^ 1][tid + jm]     = s;
        buf[srcb ^ 1][tid + jm + m] = dw;
        __syncthreads();
        srcb ^= 1;
    }

    float2 v = buf[srcb][tid];
    float msq = v.x * v.x + v.y * v.y;
    mag[((size_t)b * NBINS + tid) * NFRAMES + t] = sqrtf(fmaxf(msq, EPS32));
    if (tid == 0) {
        float2 v5 = buf[srcb][512];
        float m5 = v5.x * v5.x + v5.y * v5.y;
        mag[((size_t)b * NBINS + 512) * NFRAMES + t] = sqrtf(fmaxf(m5, EPS32));
    }
}

// ---------------------------------------------------------- weight norm ----
__global__ __launch_bounds__(256) void wnorm_kernel(const float* __restrict__ v,
                                                    const float* __restrict__ g,
                                                    float* __restrict__ out, int per_o)
{
    int o = blockIdx.x;
    int tid = threadIdx.x;
    __shared__ float red[256];
    const float* vo = v + (size_t)o * per_o;
    float s = 0.f;
    for (int i = tid; i < per_o; i += 256) { float x = vo[i]; s = fmaf(x, x, s); }
    red[tid] = s;
    __syncthreads();
    for (int k = 128; k > 0; k >>= 1) {
        if (tid < k) red[tid] += red[tid + k];
        __syncthreads();
    }
    float scale = g[o] / sqrtf(red[0]);
    for (int i = tid; i < per_o; i += 256) out[(size_t)o * per_o + i] = vo[i] * scale;
}

// -------------------------------------------------------------- pack A ----
// Apack[((tap*2+oh)*64 + lane)*8 + j] = wn[o = oh*16+(lane&15)][c = (lane>>4)*8+j][df][kw]
// tap = df*KW + kw. Frag-linear order: lane reads its 16B contiguous.
template<int KW>
__global__ __launch_bounds__(256) void packA_kernel(const float* __restrict__ wn,
                                                    f16* __restrict__ out)
{
    int idx = blockIdx.x * 256 + threadIdx.x;
    if (idx >= 3 * KW * 1024) return;
    int j   = idx & 7;
    int l   = (idx >> 3) & 63;
    int oh  = (idx >> 9) & 1;
    int tap = idx >> 10;
    int df  = tap / KW, kw = tap - df * KW;
    int o = oh * 16 + (l & 15);
    int c = ((l >> 4) << 3) + j;
    out[idx] = (f16)wn[((o * 32 + c) * 3 + df) * KW + kw];
}

// -------------------------------------------------------- harmonic conv ----
__global__ __launch_bounds__(256) void harmonic_kernel(const float* __restrict__ mag,
                                                       const float* __restrict__ wn,
                                                       const float* __restrict__ bias,
                                                       float* __restrict__ out,
                                                       float fr4, float fr5)
{
    int t = blockIdx.x * 256 + threadIdx.x;
    int f = blockIdx.y;
    int b = blockIdx.z;
    if (t >= NFRAMES) return;

    const float* mb = mag + (size_t)b * NBINS * NFRAMES;
    float xv[3][7];
    #pragma unroll
    for (int kw = 0; kw < 7; ++kw) {
        int tt = t + kw - 3;
        bool ok = (tt >= 0) && (tt < NFRAMES);
        float m336 = (ok && f >= 336) ? mb[(size_t)(f - 336) * NFRAMES + tt] : 0.f;
        float m337 = (ok && f >= 337) ? mb[(size_t)(f - 337) * NFRAMES + tt] : 0.f;
        xv[0][kw] = (1.f - fr4) * m336 + fr4 * m337;
        float m154 = (ok && f >= 154) ? mb[(size_t)(f - 154) * NFRAMES + tt] : 0.f;
        float m155 = (ok && f >= 155) ? mb[(size_t)(f - 155) * NFRAMES + tt] : 0.f;
        xv[1][kw] = (1.f - fr5) * m154 + fr5 * m155;
        xv[2][kw] = ok ? mb[(size_t)f * NFRAMES + tt] : 0.f;
    }

    for (int o = 0; o < 32; ++o) {
        float a = bias[o];
        #pragma unroll
        for (int ci = 0; ci < 3; ++ci) {
            int c = 4 + ci;
            #pragma unroll
            for (int kw = 0; kw < 7; ++kw)
                a = fmaf(xv[ci][kw], wn[(o * 7 + c) * 7 + kw], a);
        }
        a = (a > 0.f) ? a : 0.1f * a;
        out[(((size_t)b * 32 + o) * NBINS + f) * NFRAMES + t] = a;
    }
}

// ----------------------------------------------------------- MFMA conv ----
// 32ch -> 32ch, kernel 3 x KW, freq pad 1, time pad PW, time stride STRIDE.
// Block: 4 waves = {o-half} x {2 f-rows}; tile 32o x 2f x 64t.
// Input staged [frow][trow][c] fp16 in LDS with XOR swizzle:
//   byte ^= ((trow>>1)&3)<<4 ^ ((trow>>3)&1)<<6   (invariant under trow += 16/32,
//   so df / nfrag are pure offset: immediates with bits >= 7 only).
// Weights (packA frag-linear) held in VGPRs: NTAPS x f16x8.
template<int KW, int STRIDE, int PW, bool DO_LRELU>
__global__ __launch_bounds__(256, 3) void conv_mfma_kernel(
    const float* __restrict__ in, const f16* __restrict__ Ap,
    const float* __restrict__ bias, float* __restrict__ out,
    int Tin, int Tout)
{
    constexpr int NT    = 64;
    constexpr int TR    = NT * STRIDE + KW - 1;
    constexpr int TRP   = (TR + 1) & ~1;
    constexpr int NTAPS = 3 * KW;
    constexpr int ROWB  = TRP * 64;            // bytes per staged f-row
    __shared__ f16 lds[4 * TRP * 32];

    const int tid = threadIdx.x;
    const int t0  = blockIdx.x * NT;
    const int f0  = blockIdx.y * 2;
    const int b   = blockIdx.z;

    const float* inb = in + (size_t)b * 32 * NBINS * Tin;
    const int tbase = t0 * STRIDE - PW;
    char* ldsb = (char*)&lds[0];

    // ---- stage: rows f0-1 .. f0+2, transposed + swizzled, fp16 pairs
    constexpr int NSTG = 4 * 16 * TRP;
    for (int i = tid; i < NSTG; i += 256) {
        int trow = i % TRP;
        int cf   = i / TRP;
        int cp   = (cf & 15) << 1;   // even channel
        int frw  = cf >> 4;
        int fi = f0 - 1 + frw;
        int ti = tbase + trow;
        float v0 = 0.f, v1 = 0.f;
        if (fi >= 0 && fi < NBINS && ti >= 0 && ti < Tin) {
            const float* p = inb + ((size_t)cp * NBINS + fi) * Tin + ti;
            v0 = p[0];
            v1 = p[(size_t)NBINS * Tin];
        }
        f16x2 h; h[0] = (f16)v0; h[1] = (f16)v1;
        int byte = ((frw * TRP + trow) * 32 + cp) * 2;
        byte ^= ((trow >> 1) & 3) << 4;
        byte ^= ((trow >> 3) & 1) << 6;
        *reinterpret_cast<f16x2*>(ldsb + byte) = h;
    }

    const int lane = tid & 63;
    const int wave = tid >> 6;
    const int oh   = wave & 1;   // o-half
    const int frw  = wave >> 1;  // output f-row within tile

    // A fragments (global, L2-resident, coalesced 16B/lane)
    f16x8 a[NTAPS];
    {
        const f16* ap = Ap + oh * 512 + lane * 8;
        #pragma unroll
        for (int tap = 0; tap < NTAPS; ++tap)
            a[tap] = *reinterpret_cast<const f16x8*>(ap + tap * 1024);
    }

    // per-kw swizzled base addresses (df/nfrag via offset immediates)
    int baddr[KW];
    {
        int tln = lane & 15;
        int c0  = ((lane >> 4) << 3);
        #pragma unroll
        for (int kw = 0; kw < KW; ++kw) {
            int trow = tln * STRIDE + kw;
            int byte = ((frw * TRP + trow) * 32 + c0) * 2;
            byte ^= ((trow >> 1) & 3) << 4;
            byte ^= ((trow >> 3) & 1) << 6;
            baddr[kw] = byte;
        }
    }

    __syncthreads();

    f32x4 acc[4];
    #pragma unroll
    for (int nf = 0; nf < 4; ++nf) acc[nf] = (f32x4){0.f, 0.f, 0.f, 0.f};

    #pragma unroll
    for (int df = 0; df < 3; ++df) {
        #pragma unroll
        for (int kw = 0; kw < KW; ++kw) {
            f16x8 af = a[df * KW + kw];
            #pragma unroll
            for (int nf = 0; nf < 4; ++nf) {
                f16x8 bf = *reinterpret_cast<const f16x8*>(
                    ldsb + (baddr[kw] + df * ROWB + nf * (16 * STRIDE * 64)));
                acc[nf] = __builtin_amdgcn_mfma_f32_16x16x32_f16(af, bf, acc[nf], 0, 0, 0);
            }
        }
    }

    const int f = f0 + frw;
    if (f < NBINS) {
        const int og = oh * 16 + ((lane >> 4) << 2);
        const int tl = lane & 15;
        float bs[4];
        #pragma unroll
        for (int r = 0; r < 4; ++r) bs[r] = bias[og + r];
        #pragma unroll
        for (int nf = 0; nf < 4; ++nf) {
            int t = t0 + nf * 16 + tl;
            if (t < Tout) {
                #pragma unroll
                for (int r = 0; r < 4; ++r) {
                    float v = acc[nf][r] + bs[r];
                    if (DO_LRELU) v = (v > 0.f) ? v : 0.1f * v;
                    out[(((size_t)b * 32 + og + r) * NBINS + f) * Tout + t] = v;
                }
            }
        }
    }
}

// ------------------------------------------------------------ final conv ----
__global__ __launch_bounds__(256) void convo_kernel(const float* __restrict__ in,
                                                    const float* __restrict__ wn,
                                                    const float* __restrict__ bias,
                                                    float* __restrict__ f5,
                                                    float* __restrict__ flat)
{
    int idx = blockIdx.x * 256 + threadIdx.x;
    if (idx >= 4 * NBINS * 101) return;
    int t = idx % 101;
    int rem = idx / 101;
    int f = rem % NBINS;
    int b = rem / NBINS;

    float a = bias[0];
    const float* inb = in + (size_t)b * 32 * NBINS * 101;
    for (int c = 0; c < 32; ++c) {
        #pragma unroll
        for (int df = 0; df < 3; ++df) {
            int fi = f + df - 1;
            if (fi < 0 || fi >= NBINS) continue;
            #pragma unroll
            for (int kw = 0; kw < 3; ++kw) {
                int ti = t + kw - 1;
                if (ti < 0 || ti >= 101) continue;
                a = fmaf(inb[((size_t)c * NBINS + fi) * 101 + ti], wn[(c * 3 + df) * 3 + kw], a);
            }
        }
    }
    f5[idx] = a;
    flat[idx] = a;
}

// ------------------------------------------------------------------ launch --
extern "C" void kernel_launch(void* const* d_in, const int* in_sizes, int n_in,
                              void* d_out, int out_size, void* d_ws, size_t ws_size,
                              hipStream_t stream)
{
    const float* y  = (const float*)d_in[0];
    const float* v0 = (const float*)d_in[1];
    const float* g0 = (const float*)d_in[2];
    const float* b0 = (const float*)d_in[3];
    const float* v1 = (const float*)d_in[4];
    const float* g1 = (const float*)d_in[5];
    const float* b1 = (const float*)d_in[6];
    const float* v2 = (const float*)d_in[7];
    const float* g2 = (const float*)d_in[8];
    const float* b2 = (const float*)d_in[9];
    const float* v3 = (const float*)d_in[10];
    const float* g3 = (const float*)d_in[11];
    const float* b3 = (const float*)d_in[12];
    const float* v4 = (const float*)d_in[13];
    const float* g4 = (const float*)d_in[14];
    const float* b4 = (const float*)d_in[15];
    const float* vo = (const float*)d_in[16];
    const float* go = (const float*)d_in[17];
    const float* bo = (const float*)d_in[18];

    float* out = (float*)d_out;
    float* ws  = (float*)d_ws;

    const size_t SFLAT = (size_t)4 * NBINS * 101;
    const size_t NF0   = (size_t)4 * 32 * NBINS * 801;
    const size_t NF1   = (size_t)4 * 32 * NBINS * 401;
    const size_t NF2   = (size_t)4 * 32 * NBINS * 201;
    const size_t NF3   = (size_t)4 * 32 * NBINS * 101;
    float* oflat = out;
    float* f0 = out + SFLAT;
    float* f1 = f0 + NF0;
    float* f2 = f1 + NF1;
    float* f3 = f2 + NF2;
    float* f4 = f3 + NF3;
    float* f5 = f4 + NF3;

    // mag stashed in (not-yet-written) fmap1 region; consumed before conv1 writes it
    float* mag = f1;

    // workspace: fp32 normalized weights, then fp16 A-packs
    size_t off = 0;
    float* w0n = ws + off; off += 1568;
    float* w1n = ws + off; off += 27648;
    float* w2n = ws + off; off += 27648;
    float* w3n = ws + off; off += 27648;
    float* w4n = ws + off; off += 9216;
    float* won = ws + off; off += 288;
    f16* A1 = (f16*)(ws + off);
    f16* A2 = A1 + 27648;
    f16* A3 = A2 + 27648;
    f16* A4 = A3 + 27648;   // 9216 elements

    wnorm_kernel<<<32, 256, 0, stream>>>(v0, g0, w0n, 49);
    wnorm_kernel<<<32, 256, 0, stream>>>(v1, g1, w1n, 864);
    wnorm_kernel<<<32, 256, 0, stream>>>(v2, g2, w2n, 864);
    wnorm_kernel<<<32, 256, 0, stream>>>(v3, g3, w3n, 864);
    wnorm_kernel<<<32, 256, 0, stream>>>(v4, g4, w4n, 288);
    wnorm_kernel<<< 1, 256, 0, stream>>>(vo, go, won, 288);

    packA_kernel<9><<<108, 256, 0, stream>>>(w1n, A1);
    packA_kernel<9><<<108, 256, 0, stream>>>(w2n, A2);
    packA_kernel<9><<<108, 256, 0, stream>>>(w3n, A3);
    packA_kernel<3><<< 36, 256, 0, stream>>>(w4n, A4);

    stft_kernel<<<dim3(NFRAMES, 4), 512, 0, stream>>>(y, mag);

    double sh4 = -(1000.0 * log(0.001 * (5.0 / 7.0)) - 1000.0 * log(0.001)); // 336.472...
    double sh5 = -(1000.0 * log(0.001 * (6.0 / 7.0)) - 1000.0 * log(0.001)); // 154.150...
    float fr4 = (float)(sh4 - floor(sh4));
    float fr5 = (float)(sh5 - floor(sh5));

    harmonic_kernel<<<dim3(4, NBINS, 4), 256, 0, stream>>>(mag, w0n, b0, f0, fr4, fr5);

    conv_mfma_kernel<9, 2, 4, true><<<dim3(7, 257, 4), 256, 0, stream>>>(f0, A1, b1, f1, 801, 401);
    conv_mfma_kernel<9, 2, 4, true><<<dim3(4, 257, 4), 256, 0, stream>>>(f1, A2, b2, f2, 401, 201);
    conv_mfma_kernel<9, 2, 4, true><<<dim3(2, 257, 4), 256, 0, stream>>>(f2, A3, b3, f3, 201, 101);
    conv_mfma_kernel<3, 1, 1, true><<<dim3(2, 257, 4), 256, 0, stream>>>(f3, A4, b4, f4, 101, 101);

    convo_kernel<<<(int)((4 * NBINS * 101 + 255) / 256), 256, 0, stream>>>(f4, won, bo, f5, oflat);
}

// Round 3
// 621.407 us; speedup vs baseline: 4.2732x; 1.3345x over previous
//
#include <hip/hip_runtime.h>
#include <math.h>

#define T_SAMPLES 96000
#define NFRAMES 801
#define NBINS 513
#define EPS32 1.1920928955078125e-07f

typedef _Float16 f16;
typedef f16 f16x2 __attribute__((ext_vector_type(2)));
typedef f16 f16x8 __attribute__((ext_vector_type(8)));
typedef float f32x4 __attribute__((ext_vector_type(4)));

// ---------------------------------------------------------------- STFT ----
__global__ __launch_bounds__(512) void stft_kernel(const float* __restrict__ y,
                                                   float* __restrict__ mag)
{
    int t = blockIdx.x;   // frame 0..800
    int b = blockIdx.y;   // batch 0..3
    int tid = threadIdx.x;

    __shared__ float2 buf[2][1024];

    const float* yb = y + (size_t)b * T_SAMPLES;
    for (int n = tid; n < 1024; n += 512) {
        int j = t * 120 + n - 512;          // reflect pad 512 both sides
        if (j < 0) j = -j;
        if (j >= T_SAMPLES) j = 2 * T_SAMPLES - 2 - j;
        float v = yb[j];
        int np_ = n - 212;                  // window placed at lp=212, len 600
        float w = 0.0f;
        if (np_ >= 0 && np_ < 600)
            w = 0.5f * (1.0f - cospif((float)np_ * (1.0f / 300.0f)));
        buf[0][n] = make_float2(v * w, 0.0f);
    }
    __syncthreads();

    int srcb = 0;
    #pragma unroll
    for (int stage = 0; stage < 10; ++stage) {
        int m  = 1 << stage;
        int jm = (tid >> stage) << stage;   // j*m
        float jf = (float)jm * (1.0f / 512.0f);
        float wr = cospif(jf);
        float wi = -sinpif(jf);             // e^{-i pi j/l}
        float2 a  = buf[srcb][tid];
        float2 bb = buf[srcb][tid + 512];
        float2 s  = make_float2(a.x + bb.x, a.y + bb.y);
        float2 d  = make_float2(a.x - bb.x, a.y - bb.y);
        float2 dw = make_float2(d.x * wr - d.y * wi, d.x * wi + d.y * wr);
        buf[srcb ^ 1][tid + jm]     = s;
        buf[srcb ^ 1][tid + jm + m] = dw;
        __syncthreads();
        srcb ^= 1;
    }

    float2 v = buf[srcb][tid];
    float msq = v.x * v.x + v.y * v.y;
    mag[((size_t)b * NBINS + tid) * NFRAMES + t] = sqrtf(fmaxf(msq, EPS32));
    if (tid == 0) {
        float2 v5 = buf[srcb][512];
        float m5 = v5.x * v5.x + v5.y * v5.y;
        mag[((size_t)b * NBINS + 512) * NFRAMES + t] = sqrtf(fmaxf(m5, EPS32));
    }
}

// ---------------------------------------------------------- weight norm ----
__global__ __launch_bounds__(256) void wnorm_kernel(const float* __restrict__ v,
                                                    const float* __restrict__ g,
                                                    float* __restrict__ out, int per_o)
{
    int o = blockIdx.x;
    int tid = threadIdx.x;
    __shared__ float red[256];
    const float* vo = v + (size_t)o * per_o;
    float s = 0.f;
    for (int i = tid; i < per_o; i += 256) { float x = vo[i]; s = fmaf(x, x, s); }
    red[tid] = s;
    __syncthreads();
    for (int k = 128; k > 0; k >>= 1) {
        if (tid < k) red[tid] += red[tid + k];
        __syncthreads();
    }
    float scale = g[o] / sqrtf(red[0]);
    for (int i = tid; i < per_o; i += 256) out[(size_t)o * per_o + i] = vo[i] * scale;
}

// -------------------------------------------------------------- pack A ----
template<int KW>
__global__ __launch_bounds__(256) void packA_kernel(const float* __restrict__ wn,
                                                    f16* __restrict__ out)
{
    int idx = blockIdx.x * 256 + threadIdx.x;
    if (idx >= 3 * KW * 1024) return;
    int j   = idx & 7;
    int l   = (idx >> 3) & 63;
    int oh  = (idx >> 9) & 1;
    int tap = idx >> 10;
    int df  = tap / KW, kw = tap - df * KW;
    int o = oh * 16 + (l & 15);
    int c = ((l >> 4) << 3) + j;
    out[idx] = (f16)wn[((o * 32 + c) * 3 + df) * KW + kw];
}

// -------------------------------------------------------- harmonic conv ----
// One block per (f, b). Stage the three blended source rows (channels 4,5,6
// of the lowered tensor; 0..3 are identically zero since shift >= F) in LDS,
// then each thread computes 4 consecutive t for all 32 output channels.
__global__ __launch_bounds__(256) void harmonic_kernel(const float* __restrict__ mag,
                                                       const float* __restrict__ wn,
                                                       const float* __restrict__ bias,
                                                       float* __restrict__ out,
                                                       float fr4, float fr5)
{
    int f = blockIdx.x;
    int b = blockIdx.y;
    int tid = threadIdx.x;

    __shared__ float rows[3][808];

    const float* mb = mag + (size_t)b * NBINS * NFRAMES;

    // stage blended rows: LDS index i corresponds to tt = i - 3
    for (int i = tid; i < 808; i += 256) {
        int tt = i - 3;
        bool ok = (tt >= 0) && (tt < NFRAMES);
        float m336 = (ok && f >= 336) ? mb[(size_t)(f - 336) * NFRAMES + tt] : 0.f;
        float m337 = (ok && f >= 337) ? mb[(size_t)(f - 337) * NFRAMES + tt] : 0.f;
        float m154 = (ok && f >= 154) ? mb[(size_t)(f - 154) * NFRAMES + tt] : 0.f;
        float m155 = (ok && f >= 155) ? mb[(size_t)(f - 155) * NFRAMES + tt] : 0.f;
        float m0   = ok ? mb[(size_t)f * NFRAMES + tt] : 0.f;
        rows[0][i] = (1.f - fr4) * m336 + fr4 * m337;
        rows[1][i] = (1.f - fr5) * m154 + fr5 * m155;
        rows[2][i] = m0;
    }
    __syncthreads();

    // each thread owns t = t0 .. t0+3
    int t0 = tid * 4;
    float win[3][10];
    #pragma unroll
    for (int r = 0; r < 3; ++r)
        #pragma unroll
        for (int k = 0; k < 10; ++k) {
            int idx = t0 + k; if (idx > 807) idx = 807;
            win[r][k] = rows[r][idx];
        }

    bool full = (t0 + 3 < NFRAMES);
    bool any  = (t0 < NFRAMES);
    if (!any) return;

    size_t obase = (((size_t)b * 32) * NBINS + f) * NFRAMES + t0;
    for (int o = 0; o < 32; ++o) {
        float acc0 = bias[o], acc1 = acc0, acc2 = acc0, acc3 = acc0;
        #pragma unroll
        for (int r = 0; r < 3; ++r) {
            const float* wr = wn + (o * 7 + 4 + r) * 7;
            #pragma unroll
            for (int kw = 0; kw < 7; ++kw) {
                float w = wr[kw];
                acc0 = fmaf(win[r][kw],     w, acc0);
                acc1 = fmaf(win[r][kw + 1], w, acc1);
                acc2 = fmaf(win[r][kw + 2], w, acc2);
                acc3 = fmaf(win[r][kw + 3], w, acc3);
            }
        }
        acc0 = (acc0 > 0.f) ? acc0 : 0.1f * acc0;
        acc1 = (acc1 > 0.f) ? acc1 : 0.1f * acc1;
        acc2 = (acc2 > 0.f) ? acc2 : 0.1f * acc2;
        acc3 = (acc3 > 0.f) ? acc3 : 0.1f * acc3;
        float* p = out + obase + (size_t)o * NBINS * NFRAMES;
        if (full) {
            f32x4 v = {acc0, acc1, acc2, acc3};
            *reinterpret_cast<f32x4*>(p) = v;
        } else {
            int nrem = NFRAMES - t0;           // 1..3
            p[0] = acc0;
            if (nrem > 1) p[1] = acc1;
            if (nrem > 2) p[2] = acc2;
        }
    }
}

// ----------------------------------------------------------- MFMA conv ----
template<int KW, int STRIDE, int PW, bool DO_LRELU>
__global__ __launch_bounds__(256, 3) void conv_mfma_kernel(
    const float* __restrict__ in, const f16* __restrict__ Ap,
    const float* __restrict__ bias, float* __restrict__ out,
    int Tin, int Tout)
{
    constexpr int NT    = 64;
    constexpr int TR    = NT * STRIDE + KW - 1;
    constexpr int TRP   = (TR + 1) & ~1;
    constexpr int NTAPS = 3 * KW;
    constexpr int ROWB  = TRP * 64;            // bytes per staged f-row
    __shared__ f16 lds[4 * TRP * 32];

    const int tid = threadIdx.x;
    const int t0  = blockIdx.x * NT;
    const int f0  = blockIdx.y * 2;
    const int b   = blockIdx.z;

    const float* inb = in + (size_t)b * 32 * NBINS * Tin;
    const int tbase = t0 * STRIDE - PW;
    char* ldsb = (char*)&lds[0];

    constexpr int NSTG = 4 * 16 * TRP;
    for (int i = tid; i < NSTG; i += 256) {
        int trow = i % TRP;
        int cf   = i / TRP;
        int cp   = (cf & 15) << 1;   // even channel
        int frw  = cf >> 4;
        int fi = f0 - 1 + frw;
        int ti = tbase + trow;
        float v0 = 0.f, v1 = 0.f;
        if (fi >= 0 && fi < NBINS && ti >= 0 && ti < Tin) {
            const float* p = inb + ((size_t)cp * NBINS + fi) * Tin + ti;
            v0 = p[0];
            v1 = p[(size_t)NBINS * Tin];
        }
        f16x2 h; h[0] = (f16)v0; h[1] = (f16)v1;
        int byte = ((frw * TRP + trow) * 32 + cp) * 2;
        byte ^= ((trow >> 1) & 3) << 4;
        byte ^= ((trow >> 3) & 1) << 6;
        *reinterpret_cast<f16x2*>(ldsb + byte) = h;
    }

    const int lane = tid & 63;
    const int wave = tid >> 6;
    const int oh   = wave & 1;   // o-half
    const int frw  = wave >> 1;  // output f-row within tile

    f16x8 a[NTAPS];
    {
        const f16* ap = Ap + oh * 512 + lane * 8;
        #pragma unroll
        for (int tap = 0; tap < NTAPS; ++tap)
            a[tap] = *reinterpret_cast<const f16x8*>(ap + tap * 1024);
    }

    int baddr[KW];
    {
        int tln = lane & 15;
        int c0  = ((lane >> 4) << 3);
        #pragma unroll
        for (int kw = 0; kw < KW; ++kw) {
            int trow = tln * STRIDE + kw;
            int byte = ((frw * TRP + trow) * 32 + c0) * 2;
            byte ^= ((trow >> 1) & 3) << 4;
            byte ^= ((trow >> 3) & 1) << 6;
            baddr[kw] = byte;
        }
    }

    __syncthreads();

    f32x4 acc[4];
    #pragma unroll
    for (int nf = 0; nf < 4; ++nf) acc[nf] = (f32x4){0.f, 0.f, 0.f, 0.f};

    #pragma unroll
    for (int df = 0; df < 3; ++df) {
        #pragma unroll
        for (int kw = 0; kw < KW; ++kw) {
            f16x8 af = a[df * KW + kw];
            #pragma unroll
            for (int nf = 0; nf < 4; ++nf) {
                f16x8 bf = *reinterpret_cast<const f16x8*>(
                    ldsb + (baddr[kw] + df * ROWB + nf * (16 * STRIDE * 64)));
                acc[nf] = __builtin_amdgcn_mfma_f32_16x16x32_f16(af, bf, acc[nf], 0, 0, 0);
            }
        }
    }

    const int f = f0 + frw;
    if (f < NBINS) {
        const int og = oh * 16 + ((lane >> 4) << 2);
        const int tl = lane & 15;
        float bs[4];
        #pragma unroll
        for (int r = 0; r < 4; ++r) bs[r] = bias[og + r];
        #pragma unroll
        for (int nf = 0; nf < 4; ++nf) {
            int t = t0 + nf * 16 + tl;
            if (t < Tout) {
                #pragma unroll
                for (int r = 0; r < 4; ++r) {
                    float v = acc[nf][r] + bs[r];
                    if (DO_LRELU) v = (v > 0.f) ? v : 0.1f * v;
                    out[(((size_t)b * 32 + og + r) * NBINS + f) * Tout + t] = v;
                }
            }
        }
    }
}

// ------------------------------------------------------------ final conv ----
__global__ __launch_bounds__(256) void convo_kernel(const float* __restrict__ in,
                                                    const float* __restrict__ wn,
                                                    const float* __restrict__ bias,
                                                    float* __restrict__ f5,
                                                    float* __restrict__ flat)
{
    int idx = blockIdx.x * 256 + threadIdx.x;
    if (idx >= 4 * NBINS * 101) return;
    int t = idx % 101;
    int rem = idx / 101;
    int f = rem % NBINS;
    int b = rem / NBINS;

    float a = bias[0];
    const float* inb = in + (size_t)b * 32 * NBINS * 101;
    for (int c = 0; c < 32; ++c) {
        #pragma unroll
        for (int df = 0; df < 3; ++df) {
            int fi = f + df - 1;
            if (fi < 0 || fi >= NBINS) continue;
            #pragma unroll
            for (int kw = 0; kw < 3; ++kw) {
                int ti = t + kw - 1;
                if (ti < 0 || ti >= 101) continue;
                a = fmaf(inb[((size_t)c * NBINS + fi) * 101 + ti], wn[(c * 3 + df) * 3 + kw], a);
            }
        }
    }
    f5[idx] = a;
    flat[idx] = a;
}

// ------------------------------------------------------------------ launch --
extern "C" void kernel_launch(void* const* d_in, const int* in_sizes, int n_in,
                              void* d_out, int out_size, void* d_ws, size_t ws_size,
                              hipStream_t stream)
{
    const float* y  = (const float*)d_in[0];
    const float* v0 = (const float*)d_in[1];
    const float* g0 = (const float*)d_in[2];
    const float* b0 = (const float*)d_in[3];
    const float* v1 = (const float*)d_in[4];
    const float* g1 = (const float*)d_in[5];
    const float* b1 = (const float*)d_in[6];
    const float* v2 = (const float*)d_in[7];
    const float* g2 = (const float*)d_in[8];
    const float* b2 = (const float*)d_in[9];
    const float* v3 = (const float*)d_in[10];
    const float* g3 = (const float*)d_in[11];
    const float* b3 = (const float*)d_in[12];
    const float* v4 = (const float*)d_in[13];
    const float* g4 = (const float*)d_in[14];
    const float* b4 = (const float*)d_in[15];
    const float* vo = (const float*)d_in[16];
    const float* go = (const float*)d_in[17];
    const float* bo = (const float*)d_in[18];

    float* out = (float*)d_out;
    float* ws  = (float*)d_ws;

    const size_t SFLAT = (size_t)4 * NBINS * 101;
    const size_t NF0   = (size_t)4 * 32 * NBINS * 801;
    const size_t NF1   = (size_t)4 * 32 * NBINS * 401;
    const size_t NF2   = (size_t)4 * 32 * NBINS * 201;
    const size_t NF3   = (size_t)4 * 32 * NBINS * 101;
    float* oflat = out;
    float* f0 = out + SFLAT;
    float* f1 = f0 + NF0;
    float* f2 = f1 + NF1;
    float* f3 = f2 + NF2;
    float* f4 = f3 + NF3;
    float* f5 = f4 + NF3;

    // mag stashed in (not-yet-written) fmap1 region; consumed before conv1 writes it
    float* mag = f1;

    size_t off = 0;
    float* w0n = ws + off; off += 1568;
    float* w1n = ws + off; off += 27648;
    float* w2n = ws + off; off += 27648;
    float* w3n = ws + off; off += 27648;
    float* w4n = ws + off; off += 9216;
    float* won = ws + off; off += 288;
    f16* A1 = (f16*)(ws + off);
    f16* A2 = A1 + 27648;
    f16* A3 = A2 + 27648;
    f16* A4 = A3 + 27648;

    wnorm_kernel<<<32, 256, 0, stream>>>(v0, g0, w0n, 49);
    wnorm_kernel<<<32, 256, 0, stream>>>(v1, g1, w1n, 864);
    wnorm_kernel<<<32, 256, 0, stream>>>(v2, g2, w2n, 864);
    wnorm_kernel<<<32, 256, 0, stream>>>(v3, g3, w3n, 864);
    wnorm_kernel<<<32, 256, 0, stream>>>(v4, g4, w4n, 288);
    wnorm_kernel<<< 1, 256, 0, stream>>>(vo, go, won, 288);

    packA_kernel<9><<<108, 256, 0, stream>>>(w1n, A1);
    packA_kernel<9><<<108, 256, 0, stream>>>(w2n, A2);
    packA_kernel<9><<<108, 256, 0, stream>>>(w3n, A3);
    packA_kernel<3><<< 36, 256, 0, stream>>>(w4n, A4);

    stft_kernel<<<dim3(NFRAMES, 4), 512, 0, stream>>>(y, mag);

    double sh4 = -(1000.0 * log(0.001 * (5.0 / 7.0)) - 1000.0 * log(0.001)); // 336.472...
    double sh5 = -(1000.0 * log(0.001 * (6.0 / 7.0)) - 1000.0 * log(0.001)); // 154.150...
    float fr4 = (float)(sh4 - floor(sh4));
    float fr5 = (float)(sh5 - floor(sh5));

    harmonic_kernel<<<dim3(NBINS, 4), 256, 0, stream>>>(mag, w0n, b0, f0, fr4, fr5);

    conv_mfma_kernel<9, 2, 4, true><<<dim3(7, 257, 4), 256, 0, stream>>>(f0, A1, b1, f1, 801, 401);
    conv_mfma_kernel<9, 2, 4, true><<<dim3(4, 257, 4), 256, 0, stream>>>(f1, A2, b2, f2, 401, 201);
    conv_mfma_kernel<9, 2, 4, true><<<dim3(2, 257, 4), 256, 0, stream>>>(f2, A3, b3, f3, 201, 101);
    conv_mfma_kernel<3, 1, 1, true><<<dim3(2, 257, 4), 256, 0, stream>>>(f3, A4, b4, f4, 101, 101);

    convo_kernel<<<(int)((4 * NBINS * 101 + 255) / 256), 256, 0, stream>>>(f4, won, bo, f5, oflat);
}